// Round 5
// baseline (568.941 us; speedup 1.0000x reference)
//
#include <hip/hip_runtime.h>
#include <hip/hip_bf16.h>

#define NN 100000
#define EE 800000
#define GG 1024
#define ETOT (EE + NN)

typedef __attribute__((ext_vector_type(8))) short short8;
typedef __attribute__((ext_vector_type(4))) float floatx4;

__device__ __forceinline__ float sigmoidf_(float v) { return 1.f / (1.f + expf(-v)); }
__device__ __forceinline__ float bf2f(unsigned short u) {
    union { unsigned int i; float f; } x; x.i = ((unsigned int)u) << 16; return x.f;
}
__device__ __forceinline__ float bflo(unsigned int u) {
    union { unsigned int i; float f; } x; x.i = u << 16; return x.f;
}
__device__ __forceinline__ float bfhi(unsigned int u) {
    union { unsigned int i; float f; } x; x.i = u & 0xffff0000u; return x.f;
}
__device__ __forceinline__ unsigned short f2bf(float f) {
    union { unsigned int i; float f; } x; x.f = f;
    unsigned int r = (x.i + 0x7fff + ((x.i >> 16) & 1)) >> 16;
    return (unsigned short)r;
}

// ---------------- init ----------------
__global__ void k_zero(int* deg, int* cur, float* gsum) {
    int i = blockIdx.x * 256 + threadIdx.x;
    if (i < NN) { deg[i] = 0; cur[i] = 0; }
    if (i < GG * 64) gsum[i] = 0.f;
}

// ---------------- precompute: embeddings + weights -> bf16 ----------------
__global__ void k_prep_emb(const float* __restrict__ e0, const float* __restrict__ e1,
                           const float* __restrict__ e2, const float* __restrict__ e3,
                           const float* __restrict__ e4, const float* __restrict__ e5,
                           unsigned short* __restrict__ ebf) {
    int i = blockIdx.x * 256 + threadIdx.x;
    if (i >= 50 * 64) return;
    int row = i >> 6, c = i & 63;
    const float* tab; int r;
    if (row < 33)      { tab = e0; r = row; }
    else if (row < 38) { tab = e1; r = row - 33; }
    else if (row < 41) { tab = e2; r = row - 38; }
    else if (row < 45) { tab = e3; r = row - 41; }
    else if (row < 47) { tab = e4; r = row - 45; }
    else               { tab = e5; r = row - 47; }
    ebf[i] = f2bf(tab[r * 64 + c]);
}

// W [K][256] f32 -> frag-ordered bf16: Wt[((ks*16+cf)*64 + lane)*8 + j]
template <int KS>
__global__ void k_prep_w(const float* __restrict__ W, unsigned short* __restrict__ Wt) {
    int tid = blockIdx.x * 256 + threadIdx.x;
    if (tid >= KS * 16 * 64) return;
    int l = tid & 63;
    int cf = (tid >> 6) & 15;
    int ks = tid >> 10;
    int kbase = ks * 32 + (l >> 4) * 8;
    int col = cf * 16 + (l & 15);
    unsigned short* o = Wt + (size_t)tid * 8;
#pragma unroll
    for (int j = 0; j < 8; j++) o[j] = f2bf(W[(size_t)(kbase + j) * 256 + col]);
}

// ---------------- CSR build ----------------
__global__ void k_hist(const int* __restrict__ ei, int* __restrict__ deg) {
    int e = blockIdx.x * 256 + threadIdx.x;
    if (e >= ETOT) return;
    int d = (e < EE) ? ei[EE + e] : (e - EE);
    atomicAdd(&deg[d], 1);
}

__global__ void k_scan1(const int* __restrict__ deg, int* __restrict__ offs,
                        int* __restrict__ bsum) {
    __shared__ int l[256];
    int i = blockIdx.x * 256 + threadIdx.x;
    l[threadIdx.x] = (i < NN) ? deg[i] : 0;
    __syncthreads();
    if (threadIdx.x == 0) {
        int run = 0;
        for (int j = 0; j < 256; j++) { int t = l[j]; l[j] = run; run += t; }
        bsum[blockIdx.x] = run;
    }
    __syncthreads();
    if (i < NN) offs[i] = l[threadIdx.x];
}

__global__ void k_scan2(int* __restrict__ bsum, int nb, int* __restrict__ offs) {
    int lane = threadIdx.x;  // 64 threads
    int run = 0;
    for (int base = 0; base < nb; base += 64) {
        int i = base + lane;
        int orig = (i < nb) ? bsum[i] : 0;
        int v = orig;
#pragma unroll
        for (int o = 1; o < 64; o <<= 1) {
            int t = __shfl_up(v, o);
            if (lane >= o) v += t;
        }
        if (i < nb) bsum[i] = run + v - orig;   // exclusive
        run += __shfl(v, 63);
    }
    if (lane == 0) offs[NN] = run;
}

__global__ void k_scan3(int* __restrict__ offs, const int* __restrict__ bsum) {
    int i = blockIdx.x * 256 + threadIdx.x;
    if (i < NN) offs[i] += bsum[blockIdx.x];
}

__global__ void k_scatter(const int* __restrict__ ei, const int* __restrict__ offs,
                          int* __restrict__ cur, int* __restrict__ csrc) {
    int e = blockIdx.x * 256 + threadIdx.x;
    if (e >= ETOT) return;
    int s, d;
    if (e < EE) { s = ei[e]; d = ei[EE + e]; }
    else { s = e - EE; d = e - EE; }
    int p = atomicAdd(&cur[d], 1);
    csrc[offs[d] + p] = s;
}

// ---------------- bf16 MFMA GEMM: C[M,256] = A[M,K] @ W[K,256] ----------------
template <int MODE, int KSTEPS>
__global__ __launch_bounds__(256) void k_gemm_mfma(const int* __restrict__ x,
                                                   const unsigned short* __restrict__ ebf,
                                                   const unsigned short* __restrict__ Abf,
                                                   const unsigned short* __restrict__ Wt,
                                                   unsigned short* __restrict__ Cb, int M) {
    __shared__ __align__(16) unsigned short As[128 * 40];
    int tid = threadIdx.x;
    int rowBase = blockIdx.y * 128;
    int colBase = blockIdx.x * 64;
    int l = tid & 63, w = tid >> 6;
    int strip = w * 32;
    floatx4 acc[2][4] = {};

    for (int ks = 0; ks < KSTEPS; ks++) {
        {
            int r = tid >> 1, half = tid & 1;
            int row = rowBase + r;
            uint4 v0 = {0, 0, 0, 0}, v1 = {0, 0, 0, 0};
            if (row < M) {
                const unsigned short* src;
                if (MODE == 0) {
                    int t = ks >> 1, cb = (ks & 1) * 32;
                    int toff = (t == 0) ? 0 : (t == 1) ? 33 : (t == 2) ? 38
                             : (t == 3) ? 41 : (t == 4) ? 45 : 47;
                    int vi = x[row * 6 + t];
                    src = ebf + (size_t)(toff + vi) * 64 + cb + half * 16;
                } else {
                    src = Abf + (size_t)row * 128 + ks * 32 + half * 16;
                }
                v0 = *(const uint4*)src;
                v1 = *(const uint4*)(src + 8);
            }
            uint4* dst = (uint4*)&As[r * 40 + half * 16];
            dst[0] = v0; dst[1] = v1;
        }
        __syncthreads();
        short8 a0 = *(const short8*)&As[(strip + (l & 15)) * 40 + (l >> 4) * 8];
        short8 a1 = *(const short8*)&As[(strip + 16 + (l & 15)) * 40 + (l >> 4) * 8];
        const short8* bp = (const short8*)(Wt + ((size_t)(ks * 16 + (colBase >> 4)) * 64 + l) * 8);
#pragma unroll
        for (int cf = 0; cf < 4; cf++) {
            short8 b = bp[cf * 64];
            acc[0][cf] = __builtin_amdgcn_mfma_f32_16x16x32_bf16(a0, b, acc[0][cf], 0, 0, 0);
            acc[1][cf] = __builtin_amdgcn_mfma_f32_16x16x32_bf16(a1, b, acc[1][cf], 0, 0, 0);
        }
        __syncthreads();
    }
#pragma unroll
    for (int rf = 0; rf < 2; rf++)
#pragma unroll
        for (int cf = 0; cf < 4; cf++)
#pragma unroll
            for (int i = 0; i < 4; i++) {
                int row = rowBase + strip + rf * 16 + (l >> 4) * 4 + i;
                int col = colBase + cf * 16 + (l & 15);
                if (row < M) Cb[(size_t)row * 256 + col] = f2bf(acc[rf][cf][i]);
            }
}

// ---------------- per-(node,head) attention dots (bf16 xw) ----------------
template <int H, int C>
__global__ void k_sd(const unsigned short* __restrict__ xwb, const float* __restrict__ a_src,
                     const float* __restrict__ a_dst, float* __restrict__ s,
                     float* __restrict__ dv) {
    int gtid = blockIdx.x * 256 + threadIdx.x;
    int wid = gtid >> 6;
    int lane = threadIdx.x & 63;
    if (wid >= NN * H) return;
    int n = wid / H, h = wid % H;
    const unsigned short* base = xwb + (size_t)n * H * C + h * C;
    float vs = 0.f, vd = 0.f;
    for (int c = lane; c < C; c += 64) {
        float v = bf2f(base[c]);
        vs += v * a_src[h * C + c];
        vd += v * a_dst[h * C + c];
    }
    for (int o = 32; o; o >>= 1) { vs += __shfl_down(vs, o); vd += __shfl_down(vd, o); }
    if (lane == 0) { s[wid] = vs; dv[wid] = vd; }
}

// ------- layer-1 aggregation: group-gather (16 lanes/edge, uint4) -------
__global__ void k_agg1(const unsigned short* __restrict__ xwb, const float* __restrict__ s,
                       const float* __restrict__ dvec, const int* __restrict__ offs,
                       const int* __restrict__ csrc, const float* __restrict__ b1,
                       unsigned short* __restrict__ h1b) {
    __shared__ float tmp[2][128];
    int n = blockIdx.x;
    int wv = threadIdx.x >> 6;   // head
    int lane = threadIdx.x & 63;
    int grp = lane >> 4, gl = lane & 15;
    int start = offs[n], end = offs[n + 1];
    int deg = end - start;
    float dn = dvec[n * 2 + wv];
    float acc[8] = {};
    float wsum = 0.f;

    if (deg <= 64) {
        int sn = 0; float e = -1e30f;
        if (lane < deg) {
            sn = csrc[start + lane];
            e = s[sn * 2 + wv] + dn;
            e = (e > 0.f) ? e : 0.2f * e;
        }
        float m = e;
#pragma unroll
        for (int o = 32; o; o >>= 1) m = fmaxf(m, __shfl_xor(m, o));
        float w = (lane < deg) ? __expf(e - m) : 0.f;
        wsum = w;
        int steps = (deg + 3) >> 2;
        for (int t = 0; t < steps; t++) {
            int j = t * 4 + grp;
            float wj = __shfl(w, j);
            int snj = __shfl(sn, j);
            if (j < deg) {
                uint4 v = *(const uint4*)(xwb + (size_t)snj * 256 + wv * 128 + gl * 8);
                acc[0] += wj * bflo(v.x); acc[1] += wj * bfhi(v.x);
                acc[2] += wj * bflo(v.y); acc[3] += wj * bfhi(v.y);
                acc[4] += wj * bflo(v.z); acc[5] += wj * bfhi(v.z);
                acc[6] += wj * bflo(v.w); acc[7] += wj * bfhi(v.w);
            }
        }
    } else {
        float m = -1e30f;
        for (int i = start + lane; i < end; i += 64) {
            int sn2 = csrc[i];
            float e = s[sn2 * 2 + wv] + dn;
            e = (e > 0.f) ? e : 0.2f * e;
            m = fmaxf(m, e);
        }
#pragma unroll
        for (int o = 32; o; o >>= 1) m = fmaxf(m, __shfl_xor(m, o));
        for (int base = start; base < end; base += 64) {
            int cnt = min(64, end - base);
            int sn = 0; float w = 0.f;
            if (lane < cnt) {
                sn = csrc[base + lane];
                float e = s[sn * 2 + wv] + dn;
                e = (e > 0.f) ? e : 0.2f * e;
                w = __expf(e - m);
            }
            wsum += w;
            int steps = (cnt + 3) >> 2;
            for (int t = 0; t < steps; t++) {
                int j = t * 4 + grp;
                float wj = __shfl(w, j);
                int snj = __shfl(sn, j);
                if (j < cnt) {
                    uint4 v = *(const uint4*)(xwb + (size_t)snj * 256 + wv * 128 + gl * 8);
                    acc[0] += wj * bflo(v.x); acc[1] += wj * bfhi(v.x);
                    acc[2] += wj * bflo(v.y); acc[3] += wj * bfhi(v.y);
                    acc[4] += wj * bflo(v.z); acc[5] += wj * bfhi(v.z);
                    acc[6] += wj * bflo(v.w); acc[7] += wj * bfhi(v.w);
                }
            }
        }
    }
#pragma unroll
    for (int o = 32; o >= 16; o >>= 1)
#pragma unroll
        for (int k = 0; k < 8; k++) acc[k] += __shfl_xor(acc[k], o);
#pragma unroll
    for (int o = 32; o; o >>= 1) wsum += __shfl_xor(wsum, o);
    float inv = 1.f / (wsum + 1e-16f);
    if (grp == 0) {
#pragma unroll
        for (int k = 0; k < 8; k++) tmp[wv][gl * 8 + k] = acc[k] * inv;
    }
    __syncthreads();
    if (wv == 0) {
        h1b[(size_t)n * 128 + lane] =
            f2bf(sigmoidf_(0.5f * (tmp[0][lane] + tmp[1][lane]) + b1[lane]));
        h1b[(size_t)n * 128 + 64 + lane] =
            f2bf(sigmoidf_(0.5f * (tmp[0][64 + lane] + tmp[1][64 + lane]) + b1[64 + lane]));
    }
}

// ------- layer-2 aggregation: group-gather (8 lanes/edge, uint4) + pool -------
__global__ void k_agg2(const unsigned short* __restrict__ xwb, const float* __restrict__ s,
                       const float* __restrict__ dvec, const int* __restrict__ offs,
                       const int* __restrict__ csrc, const float* __restrict__ b2,
                       const int* __restrict__ batch, float* __restrict__ gsum) {
    __shared__ float tmp[4][64];
    int n = blockIdx.x;
    int wv = threadIdx.x >> 6;   // head
    int lane = threadIdx.x & 63;
    int grp = lane >> 3, gl = lane & 7;
    int start = offs[n], end = offs[n + 1];
    int deg = end - start;
    float dn = dvec[n * 4 + wv];
    float acc[8] = {};
    float wsum = 0.f;

    if (deg <= 64) {
        int sn = 0; float e = -1e30f;
        if (lane < deg) {
            sn = csrc[start + lane];
            e = s[sn * 4 + wv] + dn;
            e = (e > 0.f) ? e : 0.2f * e;
        }
        float m = e;
#pragma unroll
        for (int o = 32; o; o >>= 1) m = fmaxf(m, __shfl_xor(m, o));
        float w = (lane < deg) ? __expf(e - m) : 0.f;
        wsum = w;
        int steps = (deg + 7) >> 3;
        for (int t = 0; t < steps; t++) {
            int j = t * 8 + grp;
            float wj = __shfl(w, j);
            int snj = __shfl(sn, j);
            if (j < deg) {
                uint4 v = *(const uint4*)(xwb + (size_t)snj * 256 + wv * 64 + gl * 8);
                acc[0] += wj * bflo(v.x); acc[1] += wj * bfhi(v.x);
                acc[2] += wj * bflo(v.y); acc[3] += wj * bfhi(v.y);
                acc[4] += wj * bflo(v.z); acc[5] += wj * bfhi(v.z);
                acc[6] += wj * bflo(v.w); acc[7] += wj * bfhi(v.w);
            }
        }
    } else {
        float m = -1e30f;
        for (int i = start + lane; i < end; i += 64) {
            int sn2 = csrc[i];
            float e = s[sn2 * 4 + wv] + dn;
            e = (e > 0.f) ? e : 0.2f * e;
            m = fmaxf(m, e);
        }
#pragma unroll
        for (int o = 32; o; o >>= 1) m = fmaxf(m, __shfl_xor(m, o));
        for (int base = start; base < end; base += 64) {
            int cnt = min(64, end - base);
            int sn = 0; float w = 0.f;
            if (lane < cnt) {
                sn = csrc[base + lane];
                float e = s[sn * 4 + wv] + dn;
                e = (e > 0.f) ? e : 0.2f * e;
                w = __expf(e - m);
            }
            wsum += w;
            int steps = (cnt + 7) >> 3;
            for (int t = 0; t < steps; t++) {
                int j = t * 8 + grp;
                float wj = __shfl(w, j);
                int snj = __shfl(sn, j);
                if (j < cnt) {
                    uint4 v = *(const uint4*)(xwb + (size_t)snj * 256 + wv * 64 + gl * 8);
                    acc[0] += wj * bflo(v.x); acc[1] += wj * bfhi(v.x);
                    acc[2] += wj * bflo(v.y); acc[3] += wj * bfhi(v.y);
                    acc[4] += wj * bflo(v.z); acc[5] += wj * bfhi(v.z);
                    acc[6] += wj * bflo(v.w); acc[7] += wj * bfhi(v.w);
                }
            }
        }
    }
#pragma unroll
    for (int o = 32; o >= 8; o >>= 1)
#pragma unroll
        for (int k = 0; k < 8; k++) acc[k] += __shfl_xor(acc[k], o);
#pragma unroll
    for (int o = 32; o; o >>= 1) wsum += __shfl_xor(wsum, o);
    float inv = 1.f / (wsum + 1e-16f);
    if (grp == 0) {
#pragma unroll
        for (int k = 0; k < 8; k++) tmp[wv][gl * 8 + k] = acc[k] * inv;
    }
    __syncthreads();
    if (wv == 0) {
        float v = 0.25f * (tmp[0][lane] + tmp[1][lane] + tmp[2][lane] + tmp[3][lane]) + b2[lane];
        atomicAdd(&gsum[batch[n] * 64 + lane], sigmoidf_(v));
    }
}

// ---------------- final ----------------
__global__ void k_final(const float* __restrict__ gsum, const float* __restrict__ lw,
                        const float* __restrict__ lb, float* __restrict__ out) {
    int g = blockIdx.x;
    int lane = threadIdx.x;
    float v = gsum[g * 64 + lane] * lw[lane];
    for (int o = 32; o; o >>= 1) v += __shfl_down(v, o);
    if (lane == 0) out[g] = sigmoidf_(v + lb[0]);
}

// ---------------- launch ----------------
extern "C" void kernel_launch(void* const* d_in, const int* in_sizes, int n_in,
                              void* d_out, int out_size, void* d_ws, size_t ws_size,
                              hipStream_t stream) {
    const int* x   = (const int*)d_in[0];
    const int* ei  = (const int*)d_in[1];
    const int* bat = (const int*)d_in[3];
    const float* e0 = (const float*)d_in[4];
    const float* e1 = (const float*)d_in[5];
    const float* e2 = (const float*)d_in[6];
    const float* e3 = (const float*)d_in[7];
    const float* e4 = (const float*)d_in[8];
    const float* e5 = (const float*)d_in[9];
    const float* W1 = (const float*)d_in[10];
    const float* as1 = (const float*)d_in[11];
    const float* ad1 = (const float*)d_in[12];
    const float* b1 = (const float*)d_in[13];
    const float* W2 = (const float*)d_in[14];
    const float* as2 = (const float*)d_in[15];
    const float* ad2 = (const float*)d_in[16];
    const float* b2 = (const float*)d_in[17];
    const float* lw = (const float*)d_in[18];
    const float* lb = (const float*)d_in[19];
    float* out = (float*)d_out;

    char* base = (char*)d_ws;
    size_t off = 0;
    auto alloc = [&](size_t bytes) {
        size_t o = off;
        off = (off + bytes + 255) & ~(size_t)255;
        return o;
    };
    unsigned short* xwb = (unsigned short*)(base + alloc((size_t)NN * 256 * 2));
    unsigned short* h1b = (unsigned short*)(base + alloc((size_t)NN * 128 * 2));
    float* sbuf = (float*)(base + alloc((size_t)NN * 4 * 4));
    float* dbuf = (float*)(base + alloc((size_t)NN * 4 * 4));
    float* gsum = (float*)(base + alloc((size_t)GG * 64 * 4));
    int* deg  = (int*)(base + alloc((size_t)NN * 4));
    int* offs = (int*)(base + alloc((size_t)(NN + 1) * 4));
    int* cur  = (int*)(base + alloc((size_t)NN * 4));
    int* csrc = (int*)(base + alloc((size_t)ETOT * 4));
    int* bsum = (int*)(base + alloc((size_t)512 * 4));
    unsigned short* ebf = (unsigned short*)(base + alloc((size_t)50 * 64 * 2));
    unsigned short* Wt1 = (unsigned short*)(base + alloc((size_t)384 * 256 * 2));
    unsigned short* Wt2 = (unsigned short*)(base + alloc((size_t)128 * 256 * 2));

    const int nb = (NN + 255) / 256;  // 391

    k_zero<<<nb, 256, 0, stream>>>(deg, cur, gsum);
    k_prep_emb<<<(50 * 64 + 255) / 256, 256, 0, stream>>>(e0, e1, e2, e3, e4, e5, ebf);
    k_prep_w<12><<<(12 * 16 * 64 + 255) / 256, 256, 0, stream>>>(W1, Wt1);
    k_prep_w<4><<<(4 * 16 * 64 + 255) / 256, 256, 0, stream>>>(W2, Wt2);
    k_hist<<<(ETOT + 255) / 256, 256, 0, stream>>>(ei, deg);
    k_scan1<<<nb, 256, 0, stream>>>(deg, offs, bsum);
    k_scan2<<<1, 64, 0, stream>>>(bsum, nb, offs);
    k_scan3<<<nb, 256, 0, stream>>>(offs, bsum);
    k_scatter<<<(ETOT + 255) / 256, 256, 0, stream>>>(ei, offs, cur, csrc);

    // layer 1
    {
        dim3 grid(4, (NN + 127) / 128);
        k_gemm_mfma<0, 12><<<grid, 256, 0, stream>>>(x, ebf, nullptr, Wt1, xwb, NN);
    }
    k_sd<2, 128><<<(NN * 2 * 64) / 256, 256, 0, stream>>>(xwb, as1, ad1, sbuf, dbuf);
    k_agg1<<<NN, 128, 0, stream>>>(xwb, sbuf, dbuf, offs, csrc, b1, h1b);

    // layer 2
    {
        dim3 grid(4, (NN + 127) / 128);
        k_gemm_mfma<1, 4><<<grid, 256, 0, stream>>>(x, ebf, h1b, Wt2, xwb, NN);
    }
    k_sd<4, 64><<<(NN * 4 * 64) / 256, 256, 0, stream>>>(xwb, as2, ad2, sbuf, dbuf);
    k_agg2<<<NN, 256, 0, stream>>>(xwb, sbuf, dbuf, offs, csrc, b2, bat, gsum);

    // final
    k_final<<<GG, 64, 0, stream>>>(gsum, lw, lb, out);
}

// Round 6
// 439.933 us; speedup vs baseline: 1.2932x; 1.2932x over previous
//
#include <hip/hip_runtime.h>
#include <hip/hip_bf16.h>

#define NN 100000
#define EE 800000
#define GG 1024
#define ETOT (EE + NN)

typedef __attribute__((ext_vector_type(8))) short short8;
typedef __attribute__((ext_vector_type(4))) float floatx4;

__device__ __forceinline__ float sigmoidf_(float v) { return 1.f / (1.f + expf(-v)); }
__device__ __forceinline__ float bf2f(unsigned short u) {
    union { unsigned int i; float f; } x; x.i = ((unsigned int)u) << 16; return x.f;
}
__device__ __forceinline__ float bflo(unsigned int u) {
    union { unsigned int i; float f; } x; x.i = u << 16; return x.f;
}
__device__ __forceinline__ float bfhi(unsigned int u) {
    union { unsigned int i; float f; } x; x.i = u & 0xffff0000u; return x.f;
}
__device__ __forceinline__ unsigned short f2bf(float f) {
    union { unsigned int i; float f; } x; x.f = f;
    unsigned int r = (x.i + 0x7fff + ((x.i >> 16) & 1)) >> 16;
    return (unsigned short)r;
}
__device__ __forceinline__ float rl_f(float v, int j) {
    return __int_as_float(__builtin_amdgcn_readlane(__float_as_int(v), j));
}
__device__ __forceinline__ int rl_i(int v, int j) {
    return __builtin_amdgcn_readlane(v, j);
}
__device__ __forceinline__ float lrelu(float e) { return (e > 0.f) ? e : 0.2f * e; }

// ---------------- init ----------------
__global__ void k_zero(int* deg, int* cur, float* gsum) {
    int i = blockIdx.x * 256 + threadIdx.x;
    if (i < NN) { deg[i] = 0; cur[i] = 0; }
    if (i < GG * 64) gsum[i] = 0.f;
}

// ---------------- precompute: embeddings + weights -> bf16 ----------------
__global__ void k_prep_emb(const float* __restrict__ e0, const float* __restrict__ e1,
                           const float* __restrict__ e2, const float* __restrict__ e3,
                           const float* __restrict__ e4, const float* __restrict__ e5,
                           unsigned short* __restrict__ ebf) {
    int i = blockIdx.x * 256 + threadIdx.x;
    if (i >= 50 * 64) return;
    int row = i >> 6, c = i & 63;
    const float* tab; int r;
    if (row < 33)      { tab = e0; r = row; }
    else if (row < 38) { tab = e1; r = row - 33; }
    else if (row < 41) { tab = e2; r = row - 38; }
    else if (row < 45) { tab = e3; r = row - 41; }
    else if (row < 47) { tab = e4; r = row - 45; }
    else               { tab = e5; r = row - 47; }
    ebf[i] = f2bf(tab[r * 64 + c]);
}

// W [K][256] f32 -> frag-ordered bf16: Wt[((ks*16+cf)*64 + lane)*8 + j]
template <int KS>
__global__ void k_prep_w(const float* __restrict__ W, unsigned short* __restrict__ Wt) {
    int tid = blockIdx.x * 256 + threadIdx.x;
    if (tid >= KS * 16 * 64) return;
    int l = tid & 63;
    int cf = (tid >> 6) & 15;
    int ks = tid >> 10;
    int kbase = ks * 32 + (l >> 4) * 8;
    int col = cf * 16 + (l & 15);
    unsigned short* o = Wt + (size_t)tid * 8;
#pragma unroll
    for (int j = 0; j < 8; j++) o[j] = f2bf(W[(size_t)(kbase + j) * 256 + col]);
}

// ---------------- CSR build ----------------
__global__ void k_hist(const int* __restrict__ ei, int* __restrict__ deg) {
    int e = blockIdx.x * 256 + threadIdx.x;
    if (e >= ETOT) return;
    int d = (e < EE) ? ei[EE + e] : (e - EE);
    atomicAdd(&deg[d], 1);
}

__global__ void k_scan1(const int* __restrict__ deg, int* __restrict__ offs,
                        int* __restrict__ bsum) {
    __shared__ int l[256];
    int i = blockIdx.x * 256 + threadIdx.x;
    l[threadIdx.x] = (i < NN) ? deg[i] : 0;
    __syncthreads();
    if (threadIdx.x == 0) {
        int run = 0;
        for (int j = 0; j < 256; j++) { int t = l[j]; l[j] = run; run += t; }
        bsum[blockIdx.x] = run;
    }
    __syncthreads();
    if (i < NN) offs[i] = l[threadIdx.x];
}

__global__ void k_scan2(int* __restrict__ bsum, int nb, int* __restrict__ offs) {
    int lane = threadIdx.x;  // 64 threads
    int run = 0;
    for (int base = 0; base < nb; base += 64) {
        int i = base + lane;
        int orig = (i < nb) ? bsum[i] : 0;
        int v = orig;
#pragma unroll
        for (int o = 1; o < 64; o <<= 1) {
            int t = __shfl_up(v, o);
            if (lane >= o) v += t;
        }
        if (i < nb) bsum[i] = run + v - orig;   // exclusive
        run += __shfl(v, 63);
    }
    if (lane == 0) offs[NN] = run;
}

__global__ void k_scan3(int* __restrict__ offs, const int* __restrict__ bsum) {
    int i = blockIdx.x * 256 + threadIdx.x;
    if (i < NN) offs[i] += bsum[blockIdx.x];
}

__global__ void k_scatter(const int* __restrict__ ei, const int* __restrict__ offs,
                          int* __restrict__ cur, int* __restrict__ csrc) {
    int e = blockIdx.x * 256 + threadIdx.x;
    if (e >= ETOT) return;
    int s, d;
    if (e < EE) { s = ei[e]; d = ei[EE + e]; }
    else { s = e - EE; d = e - EE; }
    int p = atomicAdd(&cur[d], 1);
    csrc[offs[d] + p] = s;
}

// ---------------- bf16 MFMA GEMM: C[M,256] = A[M,K] @ W[K,256] ----------------
template <int MODE, int KSTEPS>
__global__ __launch_bounds__(256) void k_gemm_mfma(const int* __restrict__ x,
                                                   const unsigned short* __restrict__ ebf,
                                                   const unsigned short* __restrict__ Abf,
                                                   const unsigned short* __restrict__ Wt,
                                                   unsigned short* __restrict__ Cb, int M) {
    __shared__ __align__(16) unsigned short As[128 * 40];
    int tid = threadIdx.x;
    int rowBase = blockIdx.y * 128;
    int colBase = blockIdx.x * 64;
    int l = tid & 63, w = tid >> 6;
    int strip = w * 32;
    floatx4 acc[2][4] = {};

    for (int ks = 0; ks < KSTEPS; ks++) {
        {
            int r = tid >> 1, half = tid & 1;
            int row = rowBase + r;
            uint4 v0 = {0, 0, 0, 0}, v1 = {0, 0, 0, 0};
            if (row < M) {
                const unsigned short* src;
                if (MODE == 0) {
                    int t = ks >> 1, cb = (ks & 1) * 32;
                    int toff = (t == 0) ? 0 : (t == 1) ? 33 : (t == 2) ? 38
                             : (t == 3) ? 41 : (t == 4) ? 45 : 47;
                    int vi = x[row * 6 + t];
                    src = ebf + (size_t)(toff + vi) * 64 + cb + half * 16;
                } else {
                    src = Abf + (size_t)row * 128 + ks * 32 + half * 16;
                }
                v0 = *(const uint4*)src;
                v1 = *(const uint4*)(src + 8);
            }
            uint4* dst = (uint4*)&As[r * 40 + half * 16];
            dst[0] = v0; dst[1] = v1;
        }
        __syncthreads();
        short8 a0 = *(const short8*)&As[(strip + (l & 15)) * 40 + (l >> 4) * 8];
        short8 a1 = *(const short8*)&As[(strip + 16 + (l & 15)) * 40 + (l >> 4) * 8];
        const short8* bp = (const short8*)(Wt + ((size_t)(ks * 16 + (colBase >> 4)) * 64 + l) * 8);
#pragma unroll
        for (int cf = 0; cf < 4; cf++) {
            short8 b = bp[cf * 64];
            acc[0][cf] = __builtin_amdgcn_mfma_f32_16x16x32_bf16(a0, b, acc[0][cf], 0, 0, 0);
            acc[1][cf] = __builtin_amdgcn_mfma_f32_16x16x32_bf16(a1, b, acc[1][cf], 0, 0, 0);
        }
        __syncthreads();
    }
#pragma unroll
    for (int rf = 0; rf < 2; rf++)
#pragma unroll
        for (int cf = 0; cf < 4; cf++)
#pragma unroll
            for (int i = 0; i < 4; i++) {
                int row = rowBase + strip + rf * 16 + (l >> 4) * 4 + i;
                int col = colBase + cf * 16 + (l & 15);
                if (row < M) Cb[(size_t)row * 256 + col] = f2bf(acc[rf][cf][i]);
            }
}

// ------- attention dots, wave-per-node: H heads, 256 total channels -------
template <int H>
__global__ __launch_bounds__(256) void k_sd2(const unsigned short* __restrict__ xwb,
                                             const float* __restrict__ a_src,
                                             const float* __restrict__ a_dst,
                                             float* __restrict__ s, float* __restrict__ dv) {
    const int G = 64 / H;           // lanes per head group
    int wv = threadIdx.x >> 6, lane = threadIdx.x & 63;
    int n = blockIdx.x * 4 + wv;    // grid = 25000 -> exact
    uint2 v = *(const uint2*)(xwb + (size_t)n * 256 + lane * 4);
    float4 as = ((const float4*)a_src)[lane];
    float4 ad = ((const float4*)a_dst)[lane];
    float f0 = bflo(v.x), f1 = bfhi(v.x), f2 = bflo(v.y), f3 = bfhi(v.y);
    float vs = f0 * as.x + f1 * as.y + f2 * as.z + f3 * as.w;
    float vd = f0 * ad.x + f1 * ad.y + f2 * ad.z + f3 * ad.w;
#pragma unroll
    for (int o = G / 2; o; o >>= 1) {
        vs += __shfl_xor(vs, o);
        vd += __shfl_xor(vd, o);
    }
    if ((lane & (G - 1)) == 0) {
        int h = lane / G;
        s[n * H + h] = vs;
        dv[n * H + h] = vd;
    }
}

// ------- layer-1 aggregation, wave-per-node (H=2, C=128) + mean/bias/sigmoid -------
__global__ __launch_bounds__(256) void k_agg1(const unsigned short* __restrict__ xwb,
                                              const float* __restrict__ s,
                                              const float* __restrict__ dvec,
                                              const int* __restrict__ offs,
                                              const int* __restrict__ csrc,
                                              const float* __restrict__ b1,
                                              unsigned short* __restrict__ h1b) {
    int wv = threadIdx.x >> 6, lane = threadIdx.x & 63;
    int n = blockIdx.x * 4 + wv;
    int h = lane >> 5;
    int start = offs[n], end = offs[n + 1], deg = end - start;
    float2 dn = *(const float2*)(dvec + n * 2);
    float acc0 = 0.f, acc1 = 0.f, acc2 = 0.f, acc3 = 0.f;
    float ws0, ws1;

    auto edge_acc = [&](int snj, float wj) {
        uint2 v = *(const uint2*)(xwb + (size_t)snj * 256 + lane * 4);
        acc0 += wj * bflo(v.x); acc1 += wj * bfhi(v.x);
        acc2 += wj * bflo(v.y); acc3 += wj * bfhi(v.y);
    };

    if (deg <= 64) {
        int sn = 0; float e0 = -1e30f, e1 = -1e30f;
        if (lane < deg) {
            sn = csrc[start + lane];
            float2 sv = *(const float2*)(s + sn * 2);
            e0 = lrelu(sv.x + dn.x);
            e1 = lrelu(sv.y + dn.y);
        }
        float m0 = e0, m1 = e1;
#pragma unroll
        for (int o = 32; o; o >>= 1) {
            m0 = fmaxf(m0, __shfl_xor(m0, o));
            m1 = fmaxf(m1, __shfl_xor(m1, o));
        }
        float w0 = (lane < deg) ? __expf(e0 - m0) : 0.f;
        float w1 = (lane < deg) ? __expf(e1 - m1) : 0.f;
        ws0 = w0; ws1 = w1;
#pragma unroll
        for (int o = 32; o; o >>= 1) {
            ws0 += __shfl_xor(ws0, o);
            ws1 += __shfl_xor(ws1, o);
        }
        int j = 0;
        for (; j + 1 < deg; j += 2) {
            int sa = rl_i(sn, j), sb = rl_i(sn, j + 1);
            float wa0 = rl_f(w0, j), wa1 = rl_f(w1, j);
            float wb0 = rl_f(w0, j + 1), wb1 = rl_f(w1, j + 1);
            edge_acc(sa, h ? wa1 : wa0);
            edge_acc(sb, h ? wb1 : wb0);
        }
        if (j < deg) {
            int sa = rl_i(sn, j);
            float wa0 = rl_f(w0, j), wa1 = rl_f(w1, j);
            edge_acc(sa, h ? wa1 : wa0);
        }
    } else {
        float m0 = -1e30f, m1 = -1e30f;
        for (int i = start + lane; i < end; i += 64) {
            int s2 = csrc[i];
            float2 sv = *(const float2*)(s + s2 * 2);
            m0 = fmaxf(m0, lrelu(sv.x + dn.x));
            m1 = fmaxf(m1, lrelu(sv.y + dn.y));
        }
#pragma unroll
        for (int o = 32; o; o >>= 1) {
            m0 = fmaxf(m0, __shfl_xor(m0, o));
            m1 = fmaxf(m1, __shfl_xor(m1, o));
        }
        float wl0 = 0.f, wl1 = 0.f;
        for (int base = start; base < end; base += 64) {
            int cnt = min(64, end - base);
            int sn = 0; float w0 = 0.f, w1 = 0.f;
            if (lane < cnt) {
                sn = csrc[base + lane];
                float2 sv = *(const float2*)(s + sn * 2);
                w0 = __expf(lrelu(sv.x + dn.x) - m0);
                w1 = __expf(lrelu(sv.y + dn.y) - m1);
            }
            wl0 += w0; wl1 += w1;
            for (int j = 0; j < cnt; j++) {
                int sa = rl_i(sn, j);
                float wa0 = rl_f(w0, j), wa1 = rl_f(w1, j);
                edge_acc(sa, h ? wa1 : wa0);
            }
        }
        ws0 = wl0; ws1 = wl1;
#pragma unroll
        for (int o = 32; o; o >>= 1) {
            ws0 += __shfl_xor(ws0, o);
            ws1 += __shfl_xor(ws1, o);
        }
    }
    float inv0 = 1.f / (ws0 + 1e-16f), inv1 = 1.f / (ws1 + 1e-16f);
    float inv = h ? inv1 : inv0;
    acc0 *= inv; acc1 *= inv; acc2 *= inv; acc3 *= inv;
    float p0 = __shfl_xor(acc0, 32), p1 = __shfl_xor(acc1, 32);
    float p2 = __shfl_xor(acc2, 32), p3 = __shfl_xor(acc3, 32);
    if (lane < 32) {
        float4 bb = ((const float4*)b1)[lane];
        ushort4 o;
        o.x = f2bf(sigmoidf_(0.5f * (acc0 + p0) + bb.x));
        o.y = f2bf(sigmoidf_(0.5f * (acc1 + p1) + bb.y));
        o.z = f2bf(sigmoidf_(0.5f * (acc2 + p2) + bb.z));
        o.w = f2bf(sigmoidf_(0.5f * (acc3 + p3) + bb.w));
        *(ushort4*)(h1b + (size_t)n * 128 + lane * 4) = o;
    }
}

// ------- layer-2 aggregation, wave-per-node (H=4, C=64) + mean/bias/sigmoid/pool -------
__global__ __launch_bounds__(256) void k_agg2(const unsigned short* __restrict__ xwb,
                                              const float* __restrict__ s,
                                              const float* __restrict__ dvec,
                                              const int* __restrict__ offs,
                                              const int* __restrict__ csrc,
                                              const float* __restrict__ b2,
                                              const int* __restrict__ batch,
                                              float* __restrict__ gsum) {
    int wv = threadIdx.x >> 6, lane = threadIdx.x & 63;
    int n = blockIdx.x * 4 + wv;
    int h = lane >> 4;
    int start = offs[n], end = offs[n + 1], deg = end - start;
    float4 dn = *(const float4*)(dvec + n * 4);
    float acc0 = 0.f, acc1 = 0.f, acc2 = 0.f, acc3 = 0.f;
    float ws0, ws1, ws2, ws3;

    auto edge_acc = [&](int snj, float wj) {
        uint2 v = *(const uint2*)(xwb + (size_t)snj * 256 + lane * 4);
        acc0 += wj * bflo(v.x); acc1 += wj * bfhi(v.x);
        acc2 += wj * bflo(v.y); acc3 += wj * bfhi(v.y);
    };
    auto selw = [&](float a0, float a1, float a2, float a3) {
        return (h & 2) ? ((h & 1) ? a3 : a2) : ((h & 1) ? a1 : a0);
    };

    if (deg <= 64) {
        int sn = 0;
        float e0 = -1e30f, e1 = -1e30f, e2 = -1e30f, e3 = -1e30f;
        if (lane < deg) {
            sn = csrc[start + lane];
            float4 sv = *(const float4*)(s + sn * 4);
            e0 = lrelu(sv.x + dn.x); e1 = lrelu(sv.y + dn.y);
            e2 = lrelu(sv.z + dn.z); e3 = lrelu(sv.w + dn.w);
        }
        float m0 = e0, m1 = e1, m2 = e2, m3 = e3;
#pragma unroll
        for (int o = 32; o; o >>= 1) {
            m0 = fmaxf(m0, __shfl_xor(m0, o)); m1 = fmaxf(m1, __shfl_xor(m1, o));
            m2 = fmaxf(m2, __shfl_xor(m2, o)); m3 = fmaxf(m3, __shfl_xor(m3, o));
        }
        float w0 = 0.f, w1 = 0.f, w2 = 0.f, w3 = 0.f;
        if (lane < deg) {
            w0 = __expf(e0 - m0); w1 = __expf(e1 - m1);
            w2 = __expf(e2 - m2); w3 = __expf(e3 - m3);
        }
        ws0 = w0; ws1 = w1; ws2 = w2; ws3 = w3;
#pragma unroll
        for (int o = 32; o; o >>= 1) {
            ws0 += __shfl_xor(ws0, o); ws1 += __shfl_xor(ws1, o);
            ws2 += __shfl_xor(ws2, o); ws3 += __shfl_xor(ws3, o);
        }
        int j = 0;
        for (; j + 1 < deg; j += 2) {
            int sa = rl_i(sn, j), sb = rl_i(sn, j + 1);
            float wa = selw(rl_f(w0, j), rl_f(w1, j), rl_f(w2, j), rl_f(w3, j));
            float wb = selw(rl_f(w0, j + 1), rl_f(w1, j + 1), rl_f(w2, j + 1), rl_f(w3, j + 1));
            edge_acc(sa, wa);
            edge_acc(sb, wb);
        }
        if (j < deg) {
            int sa = rl_i(sn, j);
            edge_acc(sa, selw(rl_f(w0, j), rl_f(w1, j), rl_f(w2, j), rl_f(w3, j)));
        }
    } else {
        float m0 = -1e30f, m1 = -1e30f, m2 = -1e30f, m3 = -1e30f;
        for (int i = start + lane; i < end; i += 64) {
            int s2 = csrc[i];
            float4 sv = *(const float4*)(s + s2 * 4);
            m0 = fmaxf(m0, lrelu(sv.x + dn.x)); m1 = fmaxf(m1, lrelu(sv.y + dn.y));
            m2 = fmaxf(m2, lrelu(sv.z + dn.z)); m3 = fmaxf(m3, lrelu(sv.w + dn.w));
        }
#pragma unroll
        for (int o = 32; o; o >>= 1) {
            m0 = fmaxf(m0, __shfl_xor(m0, o)); m1 = fmaxf(m1, __shfl_xor(m1, o));
            m2 = fmaxf(m2, __shfl_xor(m2, o)); m3 = fmaxf(m3, __shfl_xor(m3, o));
        }
        float wl0 = 0.f, wl1 = 0.f, wl2 = 0.f, wl3 = 0.f;
        for (int base = start; base < end; base += 64) {
            int cnt = min(64, end - base);
            int sn = 0; float w0 = 0.f, w1 = 0.f, w2 = 0.f, w3 = 0.f;
            if (lane < cnt) {
                sn = csrc[base + lane];
                float4 sv = *(const float4*)(s + sn * 4);
                w0 = __expf(lrelu(sv.x + dn.x) - m0);
                w1 = __expf(lrelu(sv.y + dn.y) - m1);
                w2 = __expf(lrelu(sv.z + dn.z) - m2);
                w3 = __expf(lrelu(sv.w + dn.w) - m3);
            }
            wl0 += w0; wl1 += w1; wl2 += w2; wl3 += w3;
            for (int j = 0; j < cnt; j++) {
                int sa = rl_i(sn, j);
                edge_acc(sa, selw(rl_f(w0, j), rl_f(w1, j), rl_f(w2, j), rl_f(w3, j)));
            }
        }
        ws0 = wl0; ws1 = wl1; ws2 = wl2; ws3 = wl3;
#pragma unroll
        for (int o = 32; o; o >>= 1) {
            ws0 += __shfl_xor(ws0, o); ws1 += __shfl_xor(ws1, o);
            ws2 += __shfl_xor(ws2, o); ws3 += __shfl_xor(ws3, o);
        }
    }
    float inv = 1.f / (selw(ws0, ws1, ws2, ws3) + 1e-16f);
    float t0 = acc0 * inv, t1 = acc1 * inv, t2 = acc2 * inv, t3 = acc3 * inv;
    t0 += __shfl_xor(t0, 16); t1 += __shfl_xor(t1, 16);
    t2 += __shfl_xor(t2, 16); t3 += __shfl_xor(t3, 16);
    t0 += __shfl_xor(t0, 32); t1 += __shfl_xor(t1, 32);
    t2 += __shfl_xor(t2, 32); t3 += __shfl_xor(t3, 32);
    if (lane < 16) {
        float4 bb = ((const float4*)b2)[lane];
        float* g = gsum + (size_t)batch[n] * 64 + lane * 4;
        atomicAdd(g + 0, sigmoidf_(0.25f * t0 + bb.x));
        atomicAdd(g + 1, sigmoidf_(0.25f * t1 + bb.y));
        atomicAdd(g + 2, sigmoidf_(0.25f * t2 + bb.z));
        atomicAdd(g + 3, sigmoidf_(0.25f * t3 + bb.w));
    }
}

// ---------------- final ----------------
__global__ void k_final(const float* __restrict__ gsum, const float* __restrict__ lw,
                        const float* __restrict__ lb, float* __restrict__ out) {
    int g = blockIdx.x;
    int lane = threadIdx.x;
    float v = gsum[g * 64 + lane] * lw[lane];
    for (int o = 32; o; o >>= 1) v += __shfl_down(v, o);
    if (lane == 0) out[g] = sigmoidf_(v + lb[0]);
}

// ---------------- launch ----------------
extern "C" void kernel_launch(void* const* d_in, const int* in_sizes, int n_in,
                              void* d_out, int out_size, void* d_ws, size_t ws_size,
                              hipStream_t stream) {
    const int* x   = (const int*)d_in[0];
    const int* ei  = (const int*)d_in[1];
    const int* bat = (const int*)d_in[3];
    const float* e0 = (const float*)d_in[4];
    const float* e1 = (const float*)d_in[5];
    const float* e2 = (const float*)d_in[6];
    const float* e3 = (const float*)d_in[7];
    const float* e4 = (const float*)d_in[8];
    const float* e5 = (const float*)d_in[9];
    const float* W1 = (const float*)d_in[10];
    const float* as1 = (const float*)d_in[11];
    const float* ad1 = (const float*)d_in[12];
    const float* b1 = (const float*)d_in[13];
    const float* W2 = (const float*)d_in[14];
    const float* as2 = (const float*)d_in[15];
    const float* ad2 = (const float*)d_in[16];
    const float* b2 = (const float*)d_in[17];
    const float* lw = (const float*)d_in[18];
    const float* lb = (const float*)d_in[19];
    float* out = (float*)d_out;

    char* base = (char*)d_ws;
    size_t off = 0;
    auto alloc = [&](size_t bytes) {
        size_t o = off;
        off = (off + bytes + 255) & ~(size_t)255;
        return o;
    };
    unsigned short* xwb = (unsigned short*)(base + alloc((size_t)NN * 256 * 2));
    unsigned short* h1b = (unsigned short*)(base + alloc((size_t)NN * 128 * 2));
    float* sbuf = (float*)(base + alloc((size_t)NN * 4 * 4));
    float* dbuf = (float*)(base + alloc((size_t)NN * 4 * 4));
    float* gsum = (float*)(base + alloc((size_t)GG * 64 * 4));
    int* deg  = (int*)(base + alloc((size_t)NN * 4));
    int* offs = (int*)(base + alloc((size_t)(NN + 1) * 4));
    int* cur  = (int*)(base + alloc((size_t)NN * 4));
    int* csrc = (int*)(base + alloc((size_t)ETOT * 4));
    int* bsum = (int*)(base + alloc((size_t)512 * 4));
    unsigned short* ebf = (unsigned short*)(base + alloc((size_t)50 * 64 * 2));
    unsigned short* Wt1 = (unsigned short*)(base + alloc((size_t)384 * 256 * 2));
    unsigned short* Wt2 = (unsigned short*)(base + alloc((size_t)128 * 256 * 2));

    const int nb = (NN + 255) / 256;  // 391
    const int nwb = NN / 4;           // 25000 wave-per-node blocks

    k_zero<<<nb, 256, 0, stream>>>(deg, cur, gsum);
    k_prep_emb<<<(50 * 64 + 255) / 256, 256, 0, stream>>>(e0, e1, e2, e3, e4, e5, ebf);
    k_prep_w<12><<<(12 * 16 * 64 + 255) / 256, 256, 0, stream>>>(W1, Wt1);
    k_prep_w<4><<<(4 * 16 * 64 + 255) / 256, 256, 0, stream>>>(W2, Wt2);
    k_hist<<<(ETOT + 255) / 256, 256, 0, stream>>>(ei, deg);
    k_scan1<<<nb, 256, 0, stream>>>(deg, offs, bsum);
    k_scan2<<<1, 64, 0, stream>>>(bsum, nb, offs);
    k_scan3<<<nb, 256, 0, stream>>>(offs, bsum);
    k_scatter<<<(ETOT + 255) / 256, 256, 0, stream>>>(ei, offs, cur, csrc);

    // layer 1
    {
        dim3 grid(4, (NN + 127) / 128);
        k_gemm_mfma<0, 12><<<grid, 256, 0, stream>>>(x, ebf, nullptr, Wt1, xwb, NN);
    }
    k_sd2<2><<<nwb, 256, 0, stream>>>(xwb, as1, ad1, sbuf, dbuf);
    k_agg1<<<nwb, 256, 0, stream>>>(xwb, sbuf, dbuf, offs, csrc, b1, h1b);

    // layer 2
    {
        dim3 grid(4, (NN + 127) / 128);
        k_gemm_mfma<1, 4><<<grid, 256, 0, stream>>>(x, ebf, h1b, Wt2, xwb, NN);
    }
    k_sd2<4><<<nwb, 256, 0, stream>>>(xwb, as2, ad2, sbuf, dbuf);
    k_agg2<<<nwb, 256, 0, stream>>>(xwb, sbuf, dbuf, offs, csrc, b2, bat, gsum);

    // final
    k_final<<<GG, 64, 0, stream>>>(gsum, lw, lb, out);
}

// Round 7
// 377.052 us; speedup vs baseline: 1.5089x; 1.1668x over previous
//
#include <hip/hip_runtime.h>
#include <hip/hip_bf16.h>

#define NN 100000
#define EE 800000
#define GG 1024
#define ETOT (EE + NN)

typedef __attribute__((ext_vector_type(8))) short short8;
typedef __attribute__((ext_vector_type(4))) float floatx4;

__device__ __forceinline__ float sigmoidf_(float v) { return 1.f / (1.f + expf(-v)); }
__device__ __forceinline__ float bflo(unsigned int u) {
    union { unsigned int i; float f; } x; x.i = u << 16; return x.f;
}
__device__ __forceinline__ float bfhi(unsigned int u) {
    union { unsigned int i; float f; } x; x.i = u & 0xffff0000u; return x.f;
}
__device__ __forceinline__ unsigned short f2bf(float f) {
    union { unsigned int i; float f; } x; x.f = f;
    unsigned int r = (x.i + 0x7fff + ((x.i >> 16) & 1)) >> 16;
    return (unsigned short)r;
}
__device__ __forceinline__ float rl_f(float v, int j) {
    return __int_as_float(__builtin_amdgcn_readlane(__float_as_int(v), j));
}
__device__ __forceinline__ int rl_i(int v, int j) {
    return __builtin_amdgcn_readlane(v, j);
}
__device__ __forceinline__ float rfl_f(float v) {
    return __int_as_float(__builtin_amdgcn_readfirstlane(__float_as_int(v)));
}
__device__ __forceinline__ float lrelu(float e) { return (e > 0.f) ? e : 0.2f * e; }

// ---------------- init ----------------
__global__ void k_zero(int* deg, int* cur, float* gsum) {
    int i = blockIdx.x * 256 + threadIdx.x;
    if (i < NN) { deg[i] = 0; cur[i] = 0; }
    if (i < GG * 64) gsum[i] = 0.f;
}

// ---------------- precompute: embeddings + weights -> bf16 ----------------
__global__ void k_prep_emb(const float* __restrict__ e0, const float* __restrict__ e1,
                           const float* __restrict__ e2, const float* __restrict__ e3,
                           const float* __restrict__ e4, const float* __restrict__ e5,
                           unsigned short* __restrict__ ebf) {
    int i = blockIdx.x * 256 + threadIdx.x;
    if (i >= 50 * 64) return;
    int row = i >> 6, c = i & 63;
    const float* tab; int r;
    if (row < 33)      { tab = e0; r = row; }
    else if (row < 38) { tab = e1; r = row - 33; }
    else if (row < 41) { tab = e2; r = row - 38; }
    else if (row < 45) { tab = e3; r = row - 41; }
    else if (row < 47) { tab = e4; r = row - 45; }
    else               { tab = e5; r = row - 47; }
    ebf[i] = f2bf(tab[r * 64 + c]);
}

// W [K][256] f32 -> frag-ordered bf16: Wt[((ks*16+cf)*64 + lane)*8 + j]
template <int KS>
__global__ void k_prep_w(const float* __restrict__ W, unsigned short* __restrict__ Wt) {
    int tid = blockIdx.x * 256 + threadIdx.x;
    if (tid >= KS * 16 * 64) return;
    int l = tid & 63;
    int cf = (tid >> 6) & 15;
    int ks = tid >> 10;
    int kbase = ks * 32 + (l >> 4) * 8;
    int col = cf * 16 + (l & 15);
    unsigned short* o = Wt + (size_t)tid * 8;
#pragma unroll
    for (int j = 0; j < 8; j++) o[j] = f2bf(W[(size_t)(kbase + j) * 256 + col]);
}

// ---------------- CSR build ----------------
__global__ void k_hist(const int* __restrict__ ei, int* __restrict__ deg) {
    int e = blockIdx.x * 256 + threadIdx.x;
    if (e >= ETOT) return;
    int d = (e < EE) ? ei[EE + e] : (e - EE);
    atomicAdd(&deg[d], 1);
}

__global__ void k_scan1(const int* __restrict__ deg, int* __restrict__ offs,
                        int* __restrict__ bsum) {
    __shared__ int l[256];
    int i = blockIdx.x * 256 + threadIdx.x;
    l[threadIdx.x] = (i < NN) ? deg[i] : 0;
    __syncthreads();
    if (threadIdx.x == 0) {
        int run = 0;
        for (int j = 0; j < 256; j++) { int t = l[j]; l[j] = run; run += t; }
        bsum[blockIdx.x] = run;
    }
    __syncthreads();
    if (i < NN) offs[i] = l[threadIdx.x];
}

__global__ void k_scan2(int* __restrict__ bsum, int nb, int* __restrict__ offs) {
    int lane = threadIdx.x;  // 64 threads
    int run = 0;
    for (int base = 0; base < nb; base += 64) {
        int i = base + lane;
        int orig = (i < nb) ? bsum[i] : 0;
        int v = orig;
#pragma unroll
        for (int o = 1; o < 64; o <<= 1) {
            int t = __shfl_up(v, o);
            if (lane >= o) v += t;
        }
        if (i < nb) bsum[i] = run + v - orig;   // exclusive
        run += __shfl(v, 63);
    }
    if (lane == 0) offs[NN] = run;
}

__global__ void k_scan3(int* __restrict__ offs, const int* __restrict__ bsum) {
    int i = blockIdx.x * 256 + threadIdx.x;
    if (i < NN) offs[i] += bsum[blockIdx.x];
}

__global__ void k_scatter(const int* __restrict__ ei, const int* __restrict__ offs,
                          int* __restrict__ cur, int* __restrict__ csrc) {
    int e = blockIdx.x * 256 + threadIdx.x;
    if (e >= ETOT) return;
    int s, d;
    if (e < EE) { s = ei[e]; d = ei[EE + e]; }
    else { s = e - EE; d = e - EE; }
    int p = atomicAdd(&cur[d], 1);
    csrc[offs[d] + p] = s;
}

// ---------------- bf16 MFMA GEMM: C[M,256] = A[M,K] @ W[K,256] ----------------
template <int MODE, int KSTEPS>
__global__ __launch_bounds__(256) void k_gemm_mfma(const int* __restrict__ x,
                                                   const unsigned short* __restrict__ ebf,
                                                   const unsigned short* __restrict__ Abf,
                                                   const unsigned short* __restrict__ Wt,
                                                   unsigned short* __restrict__ Cb, int M) {
    __shared__ __align__(16) unsigned short As[128 * 40];
    int tid = threadIdx.x;
    int rowBase = blockIdx.y * 128;
    int colBase = blockIdx.x * 64;
    int l = tid & 63, w = tid >> 6;
    int strip = w * 32;
    floatx4 acc[2][4] = {};

    for (int ks = 0; ks < KSTEPS; ks++) {
        {
            int r = tid >> 1, half = tid & 1;
            int row = rowBase + r;
            uint4 v0 = {0, 0, 0, 0}, v1 = {0, 0, 0, 0};
            if (row < M) {
                const unsigned short* src;
                if (MODE == 0) {
                    int t = ks >> 1, cb = (ks & 1) * 32;
                    int toff = (t == 0) ? 0 : (t == 1) ? 33 : (t == 2) ? 38
                             : (t == 3) ? 41 : (t == 4) ? 45 : 47;
                    int vi = x[row * 6 + t];
                    src = ebf + (size_t)(toff + vi) * 64 + cb + half * 16;
                } else {
                    src = Abf + (size_t)row * 128 + ks * 32 + half * 16;
                }
                v0 = *(const uint4*)src;
                v1 = *(const uint4*)(src + 8);
            }
            uint4* dst = (uint4*)&As[r * 40 + half * 16];
            dst[0] = v0; dst[1] = v1;
        }
        __syncthreads();
        short8 a0 = *(const short8*)&As[(strip + (l & 15)) * 40 + (l >> 4) * 8];
        short8 a1 = *(const short8*)&As[(strip + 16 + (l & 15)) * 40 + (l >> 4) * 8];
        const short8* bp = (const short8*)(Wt + ((size_t)(ks * 16 + (colBase >> 4)) * 64 + l) * 8);
#pragma unroll
        for (int cf = 0; cf < 4; cf++) {
            short8 b = bp[cf * 64];
            acc[0][cf] = __builtin_amdgcn_mfma_f32_16x16x32_bf16(a0, b, acc[0][cf], 0, 0, 0);
            acc[1][cf] = __builtin_amdgcn_mfma_f32_16x16x32_bf16(a1, b, acc[1][cf], 0, 0, 0);
        }
        __syncthreads();
    }
#pragma unroll
    for (int rf = 0; rf < 2; rf++)
#pragma unroll
        for (int cf = 0; cf < 4; cf++)
#pragma unroll
            for (int i = 0; i < 4; i++) {
                int row = rowBase + strip + rf * 16 + (l >> 4) * 4 + i;
                int col = colBase + cf * 16 + (l & 15);
                if (row < M) Cb[(size_t)row * 256 + col] = f2bf(acc[rf][cf][i]);
            }
}

// ------- attention dots, wave-per-node: H heads, 256 total channels -------
template <int H>
__global__ __launch_bounds__(256) void k_sd2(const unsigned short* __restrict__ xwb,
                                             const float* __restrict__ a_src,
                                             const float* __restrict__ a_dst,
                                             float* __restrict__ s, float* __restrict__ dv) {
    const int G = 64 / H;           // lanes per head group
    int wv = threadIdx.x >> 6, lane = threadIdx.x & 63;
    int n = blockIdx.x * 4 + wv;    // grid = 25000 -> exact
    uint2 v = *(const uint2*)(xwb + (size_t)n * 256 + lane * 4);
    float4 as = ((const float4*)a_src)[lane];
    float4 ad = ((const float4*)a_dst)[lane];
    float f0 = bflo(v.x), f1 = bfhi(v.x), f2 = bflo(v.y), f3 = bfhi(v.y);
    float vs = f0 * as.x + f1 * as.y + f2 * as.z + f3 * as.w;
    float vd = f0 * ad.x + f1 * ad.y + f2 * ad.z + f3 * ad.w;
#pragma unroll
    for (int o = G / 2; o; o >>= 1) {
        vs += __shfl_xor(vs, o);
        vd += __shfl_xor(vd, o);
    }
    if ((lane & (G - 1)) == 0) {
        int h = lane / G;
        s[n * H + h] = vs;
        dv[n * H + h] = vd;
    }
}

// ------- layer-1 aggregation, wave-per-node (H=2, C=128) + mean/bias/sigmoid -------
__global__ __launch_bounds__(256) void k_agg1(const unsigned short* __restrict__ xwb,
                                              const float* __restrict__ s,
                                              const float* __restrict__ dvec,
                                              const int* __restrict__ offs,
                                              const int* __restrict__ csrc,
                                              const float* __restrict__ b1,
                                              unsigned short* __restrict__ h1b) {
    int wv = threadIdx.x >> 6, lane = threadIdx.x & 63;
    int n = blockIdx.x * 4 + wv;
    int h = lane >> 5;
    int start = offs[n], end = offs[n + 1], deg = end - start;
    float2 dn = *(const float2*)(dvec + n * 2);
    float acc0 = 0.f, acc1 = 0.f, acc2 = 0.f, acc3 = 0.f;
    float ws0, ws1;

    // 4-deep unrolled gather-accumulate over edges [0,cnt) described by (sn,w0,w1)
    auto accum = [&](int sn, float w0, float w1, int cnt) {
        int j = 0;
        for (; j + 4 <= cnt; j += 4) {
            int sa = rl_i(sn, j), sb = rl_i(sn, j + 1);
            int sc = rl_i(sn, j + 2), sd_ = rl_i(sn, j + 3);
            uint2 va = *((const uint2*)(xwb + (size_t)sa * 256) + lane);
            uint2 vb = *((const uint2*)(xwb + (size_t)sb * 256) + lane);
            uint2 vc = *((const uint2*)(xwb + (size_t)sc * 256) + lane);
            uint2 vd = *((const uint2*)(xwb + (size_t)sd_ * 256) + lane);
            float wa = h ? rl_f(w1, j) : rl_f(w0, j);
            float wb = h ? rl_f(w1, j + 1) : rl_f(w0, j + 1);
            float wc = h ? rl_f(w1, j + 2) : rl_f(w0, j + 2);
            float wd = h ? rl_f(w1, j + 3) : rl_f(w0, j + 3);
            acc0 += wa * bflo(va.x); acc1 += wa * bfhi(va.x);
            acc2 += wa * bflo(va.y); acc3 += wa * bfhi(va.y);
            acc0 += wb * bflo(vb.x); acc1 += wb * bfhi(vb.x);
            acc2 += wb * bflo(vb.y); acc3 += wb * bfhi(vb.y);
            acc0 += wc * bflo(vc.x); acc1 += wc * bfhi(vc.x);
            acc2 += wc * bflo(vc.y); acc3 += wc * bfhi(vc.y);
            acc0 += wd * bflo(vd.x); acc1 += wd * bfhi(vd.x);
            acc2 += wd * bflo(vd.y); acc3 += wd * bfhi(vd.y);
        }
        for (; j < cnt; j++) {
            int sa = rl_i(sn, j);
            uint2 va = *((const uint2*)(xwb + (size_t)sa * 256) + lane);
            float wa = h ? rl_f(w1, j) : rl_f(w0, j);
            acc0 += wa * bflo(va.x); acc1 += wa * bfhi(va.x);
            acc2 += wa * bflo(va.y); acc3 += wa * bfhi(va.y);
        }
    };

    if (deg <= 64) {
        int sn = 0; float e0 = -1e30f, e1 = -1e30f;
        if (lane < deg) {
            sn = csrc[start + lane];
            float2 sv = *(const float2*)(s + sn * 2);
            e0 = lrelu(sv.x + dn.x);
            e1 = lrelu(sv.y + dn.y);
        }
        float m0 = e0, m1 = e1;
        if (deg <= 16) {
#pragma unroll
            for (int o = 8; o; o >>= 1) {
                m0 = fmaxf(m0, __shfl_xor(m0, o));
                m1 = fmaxf(m1, __shfl_xor(m1, o));
            }
        } else {
#pragma unroll
            for (int o = 32; o; o >>= 1) {
                m0 = fmaxf(m0, __shfl_xor(m0, o));
                m1 = fmaxf(m1, __shfl_xor(m1, o));
            }
        }
        float w0 = (lane < deg) ? __expf(e0 - m0) : 0.f;
        float w1 = (lane < deg) ? __expf(e1 - m1) : 0.f;
        ws0 = w0; ws1 = w1;
        if (deg <= 16) {
#pragma unroll
            for (int o = 8; o; o >>= 1) {
                ws0 += __shfl_xor(ws0, o);
                ws1 += __shfl_xor(ws1, o);
            }
            ws0 = rfl_f(ws0); ws1 = rfl_f(ws1);
        } else {
#pragma unroll
            for (int o = 32; o; o >>= 1) {
                ws0 += __shfl_xor(ws0, o);
                ws1 += __shfl_xor(ws1, o);
            }
        }
        accum(sn, w0, w1, deg);
    } else {
        float m0 = -1e30f, m1 = -1e30f;
        for (int i = start + lane; i < end; i += 64) {
            int s2 = csrc[i];
            float2 sv = *(const float2*)(s + s2 * 2);
            m0 = fmaxf(m0, lrelu(sv.x + dn.x));
            m1 = fmaxf(m1, lrelu(sv.y + dn.y));
        }
#pragma unroll
        for (int o = 32; o; o >>= 1) {
            m0 = fmaxf(m0, __shfl_xor(m0, o));
            m1 = fmaxf(m1, __shfl_xor(m1, o));
        }
        float wl0 = 0.f, wl1 = 0.f;
        for (int base = start; base < end; base += 64) {
            int cnt = min(64, end - base);
            int sn = 0; float w0 = 0.f, w1 = 0.f;
            if (lane < cnt) {
                sn = csrc[base + lane];
                float2 sv = *(const float2*)(s + sn * 2);
                w0 = __expf(lrelu(sv.x + dn.x) - m0);
                w1 = __expf(lrelu(sv.y + dn.y) - m1);
            }
            wl0 += w0; wl1 += w1;
            accum(sn, w0, w1, cnt);
        }
        ws0 = wl0; ws1 = wl1;
#pragma unroll
        for (int o = 32; o; o >>= 1) {
            ws0 += __shfl_xor(ws0, o);
            ws1 += __shfl_xor(ws1, o);
        }
    }
    float inv = h ? (1.f / (ws1 + 1e-16f)) : (1.f / (ws0 + 1e-16f));
    acc0 *= inv; acc1 *= inv; acc2 *= inv; acc3 *= inv;
    float p0 = __shfl_xor(acc0, 32), p1 = __shfl_xor(acc1, 32);
    float p2 = __shfl_xor(acc2, 32), p3 = __shfl_xor(acc3, 32);
    if (lane < 32) {
        float4 bb = ((const float4*)b1)[lane];
        ushort4 o;
        o.x = f2bf(sigmoidf_(0.5f * (acc0 + p0) + bb.x));
        o.y = f2bf(sigmoidf_(0.5f * (acc1 + p1) + bb.y));
        o.z = f2bf(sigmoidf_(0.5f * (acc2 + p2) + bb.z));
        o.w = f2bf(sigmoidf_(0.5f * (acc3 + p3) + bb.w));
        *(ushort4*)(h1b + (size_t)n * 128 + lane * 4) = o;
    }
}

// ------- layer-2 aggregation, wave-per-node (H=4, C=64) + mean/bias/sigmoid/pool -------
__global__ __launch_bounds__(256) void k_agg2(const unsigned short* __restrict__ xwb,
                                              const float* __restrict__ s,
                                              const float* __restrict__ dvec,
                                              const int* __restrict__ offs,
                                              const int* __restrict__ csrc,
                                              const float* __restrict__ b2,
                                              const int* __restrict__ batch,
                                              float* __restrict__ gsum) {
    __shared__ float tmp[4][64];
    int wv = threadIdx.x >> 6, lane = threadIdx.x & 63;
    int n = blockIdx.x * 4 + wv;
    int h = lane >> 4;
    int start = offs[n], end = offs[n + 1], deg = end - start;
    float4 dn = *(const float4*)(dvec + n * 4);
    float acc0 = 0.f, acc1 = 0.f, acc2 = 0.f, acc3 = 0.f;
    float ws0, ws1, ws2, ws3;

    auto selw = [&](float a0, float a1, float a2, float a3) {
        float lo = (h & 1) ? a1 : a0;
        float hi = (h & 1) ? a3 : a2;
        return (h & 2) ? hi : lo;
    };

    auto accum = [&](int sn, float w0, float w1, float w2, float w3, int cnt) {
        int j = 0;
        for (; j + 4 <= cnt; j += 4) {
            int sa = rl_i(sn, j), sb = rl_i(sn, j + 1);
            int sc = rl_i(sn, j + 2), sd_ = rl_i(sn, j + 3);
            uint2 va = *((const uint2*)(xwb + (size_t)sa * 256) + lane);
            uint2 vb = *((const uint2*)(xwb + (size_t)sb * 256) + lane);
            uint2 vc = *((const uint2*)(xwb + (size_t)sc * 256) + lane);
            uint2 vd = *((const uint2*)(xwb + (size_t)sd_ * 256) + lane);
            float wa = selw(rl_f(w0, j), rl_f(w1, j), rl_f(w2, j), rl_f(w3, j));
            float wb = selw(rl_f(w0, j + 1), rl_f(w1, j + 1), rl_f(w2, j + 1), rl_f(w3, j + 1));
            float wc = selw(rl_f(w0, j + 2), rl_f(w1, j + 2), rl_f(w2, j + 2), rl_f(w3, j + 2));
            float wd = selw(rl_f(w0, j + 3), rl_f(w1, j + 3), rl_f(w2, j + 3), rl_f(w3, j + 3));
            acc0 += wa * bflo(va.x); acc1 += wa * bfhi(va.x);
            acc2 += wa * bflo(va.y); acc3 += wa * bfhi(va.y);
            acc0 += wb * bflo(vb.x); acc1 += wb * bfhi(vb.x);
            acc2 += wb * bflo(vb.y); acc3 += wb * bfhi(vb.y);
            acc0 += wc * bflo(vc.x); acc1 += wc * bfhi(vc.x);
            acc2 += wc * bflo(vc.y); acc3 += wc * bfhi(vc.y);
            acc0 += wd * bflo(vd.x); acc1 += wd * bfhi(vd.x);
            acc2 += wd * bflo(vd.y); acc3 += wd * bfhi(vd.y);
        }
        for (; j < cnt; j++) {
            int sa = rl_i(sn, j);
            uint2 va = *((const uint2*)(xwb + (size_t)sa * 256) + lane);
            float wa = selw(rl_f(w0, j), rl_f(w1, j), rl_f(w2, j), rl_f(w3, j));
            acc0 += wa * bflo(va.x); acc1 += wa * bfhi(va.x);
            acc2 += wa * bflo(va.y); acc3 += wa * bfhi(va.y);
        }
    };

    if (deg <= 64) {
        int sn = 0;
        float e0 = -1e30f, e1 = -1e30f, e2 = -1e30f, e3 = -1e30f;
        if (lane < deg) {
            sn = csrc[start + lane];
            float4 sv = *(const float4*)(s + sn * 4);
            e0 = lrelu(sv.x + dn.x); e1 = lrelu(sv.y + dn.y);
            e2 = lrelu(sv.z + dn.z); e3 = lrelu(sv.w + dn.w);
        }
        float m0 = e0, m1 = e1, m2 = e2, m3 = e3;
        if (deg <= 16) {
#pragma unroll
            for (int o = 8; o; o >>= 1) {
                m0 = fmaxf(m0, __shfl_xor(m0, o)); m1 = fmaxf(m1, __shfl_xor(m1, o));
                m2 = fmaxf(m2, __shfl_xor(m2, o)); m3 = fmaxf(m3, __shfl_xor(m3, o));
            }
        } else {
#pragma unroll
            for (int o = 32; o; o >>= 1) {
                m0 = fmaxf(m0, __shfl_xor(m0, o)); m1 = fmaxf(m1, __shfl_xor(m1, o));
                m2 = fmaxf(m2, __shfl_xor(m2, o)); m3 = fmaxf(m3, __shfl_xor(m3, o));
            }
        }
        float w0 = 0.f, w1 = 0.f, w2 = 0.f, w3 = 0.f;
        if (lane < deg) {
            w0 = __expf(e0 - m0); w1 = __expf(e1 - m1);
            w2 = __expf(e2 - m2); w3 = __expf(e3 - m3);
        }
        ws0 = w0; ws1 = w1; ws2 = w2; ws3 = w3;
        if (deg <= 16) {
#pragma unroll
            for (int o = 8; o; o >>= 1) {
                ws0 += __shfl_xor(ws0, o); ws1 += __shfl_xor(ws1, o);
                ws2 += __shfl_xor(ws2, o); ws3 += __shfl_xor(ws3, o);
            }
            ws0 = rfl_f(ws0); ws1 = rfl_f(ws1);
            ws2 = rfl_f(ws2); ws3 = rfl_f(ws3);
        } else {
#pragma unroll
            for (int o = 32; o; o >>= 1) {
                ws0 += __shfl_xor(ws0, o); ws1 += __shfl_xor(ws1, o);
                ws2 += __shfl_xor(ws2, o); ws3 += __shfl_xor(ws3, o);
            }
        }
        accum(sn, w0, w1, w2, w3, deg);
    } else {
        float m0 = -1e30f, m1 = -1e30f, m2 = -1e30f, m3 = -1e30f;
        for (int i = start + lane; i < end; i += 64) {
            int s2 = csrc[i];
            float4 sv = *(const float4*)(s + s2 * 4);
            m0 = fmaxf(m0, lrelu(sv.x + dn.x)); m1 = fmaxf(m1, lrelu(sv.y + dn.y));
            m2 = fmaxf(m2, lrelu(sv.z + dn.z)); m3 = fmaxf(m3, lrelu(sv.w + dn.w));
        }
#pragma unroll
        for (int o = 32; o; o >>= 1) {
            m0 = fmaxf(m0, __shfl_xor(m0, o)); m1 = fmaxf(m1, __shfl_xor(m1, o));
            m2 = fmaxf(m2, __shfl_xor(m2, o)); m3 = fmaxf(m3, __shfl_xor(m3, o));
        }
        float wl0 = 0.f, wl1 = 0.f, wl2 = 0.f, wl3 = 0.f;
        for (int base = start; base < end; base += 64) {
            int cnt = min(64, end - base);
            int sn = 0; float w0 = 0.f, w1 = 0.f, w2 = 0.f, w3 = 0.f;
            if (lane < cnt) {
                sn = csrc[base + lane];
                float4 sv = *(const float4*)(s + sn * 4);
                w0 = __expf(lrelu(sv.x + dn.x) - m0);
                w1 = __expf(lrelu(sv.y + dn.y) - m1);
                w2 = __expf(lrelu(sv.z + dn.z) - m2);
                w3 = __expf(lrelu(sv.w + dn.w) - m3);
            }
            wl0 += w0; wl1 += w1; wl2 += w2; wl3 += w3;
            accum(sn, w0, w1, w2, w3, cnt);
        }
        ws0 = wl0; ws1 = wl1; ws2 = wl2; ws3 = wl3;
#pragma unroll
        for (int o = 32; o; o >>= 1) {
            ws0 += __shfl_xor(ws0, o); ws1 += __shfl_xor(ws1, o);
            ws2 += __shfl_xor(ws2, o); ws3 += __shfl_xor(ws3, o);
        }
    }
    float inv = 1.f / (selw(ws0, ws1, ws2, ws3) + 1e-16f);
    float t0 = acc0 * inv, t1 = acc1 * inv, t2 = acc2 * inv, t3 = acc3 * inv;
    // combine 4 heads: lanes {l, l+16, l+32, l+48} hold same channel offsets
    t0 += __shfl_xor(t0, 16); t1 += __shfl_xor(t1, 16);
    t2 += __shfl_xor(t2, 16); t3 += __shfl_xor(t3, 16);
    t0 += __shfl_xor(t0, 32); t1 += __shfl_xor(t1, 32);
    t2 += __shfl_xor(t2, 32); t3 += __shfl_xor(t3, 32);
    if (lane < 16) {
        tmp[wv][lane * 4 + 0] = t0; tmp[wv][lane * 4 + 1] = t1;
        tmp[wv][lane * 4 + 2] = t2; tmp[wv][lane * 4 + 3] = t3;
    }
    __syncthreads();
    float v = 0.25f * tmp[wv][lane] + b2[lane];
    atomicAdd(&gsum[(size_t)batch[n] * 64 + lane], sigmoidf_(v));
}

// ---------------- final ----------------
__global__ void k_final(const float* __restrict__ gsum, const float* __restrict__ lw,
                        const float* __restrict__ lb, float* __restrict__ out) {
    int g = blockIdx.x;
    int lane = threadIdx.x;
    float v = gsum[g * 64 + lane] * lw[lane];
    for (int o = 32; o; o >>= 1) v += __shfl_down(v, o);
    if (lane == 0) out[g] = sigmoidf_(v + lb[0]);
}

// ---------------- launch ----------------
extern "C" void kernel_launch(void* const* d_in, const int* in_sizes, int n_in,
                              void* d_out, int out_size, void* d_ws, size_t ws_size,
                              hipStream_t stream) {
    const int* x   = (const int*)d_in[0];
    const int* ei  = (const int*)d_in[1];
    const int* bat = (const int*)d_in[3];
    const float* e0 = (const float*)d_in[4];
    const float* e1 = (const float*)d_in[5];
    const float* e2 = (const float*)d_in[6];
    const float* e3 = (const float*)d_in[7];
    const float* e4 = (const float*)d_in[8];
    const float* e5 = (const float*)d_in[9];
    const float* W1 = (const float*)d_in[10];
    const float* as1 = (const float*)d_in[11];
    const float* ad1 = (const float*)d_in[12];
    const float* b1 = (const float*)d_in[13];
    const float* W2 = (const float*)d_in[14];
    const float* as2 = (const float*)d_in[15];
    const float* ad2 = (const float*)d_in[16];
    const float* b2 = (const float*)d_in[17];
    const float* lw = (const float*)d_in[18];
    const float* lb = (const float*)d_in[19];
    float* out = (float*)d_out;

    char* base = (char*)d_ws;
    size_t off = 0;
    auto alloc = [&](size_t bytes) {
        size_t o = off;
        off = (off + bytes + 255) & ~(size_t)255;
        return o;
    };
    unsigned short* xwb = (unsigned short*)(base + alloc((size_t)NN * 256 * 2));
    unsigned short* h1b = (unsigned short*)(base + alloc((size_t)NN * 128 * 2));
    float* sbuf = (float*)(base + alloc((size_t)NN * 4 * 4));
    float* dbuf = (float*)(base + alloc((size_t)NN * 4 * 4));
    float* gsum = (float*)(base + alloc((size_t)GG * 64 * 4));
    int* deg  = (int*)(base + alloc((size_t)NN * 4));
    int* offs = (int*)(base + alloc((size_t)(NN + 1) * 4));
    int* cur  = (int*)(base + alloc((size_t)NN * 4));
    int* csrc = (int*)(base + alloc((size_t)ETOT * 4));
    int* bsum = (int*)(base + alloc((size_t)512 * 4));
    unsigned short* ebf = (unsigned short*)(base + alloc((size_t)50 * 64 * 2));
    unsigned short* Wt1 = (unsigned short*)(base + alloc((size_t)384 * 256 * 2));
    unsigned short* Wt2 = (unsigned short*)(base + alloc((size_t)128 * 256 * 2));

    const int nb = (NN + 255) / 256;  // 391
    const int nwb = NN / 4;           // 25000 wave-per-node blocks

    k_zero<<<nb, 256, 0, stream>>>(deg, cur, gsum);
    k_prep_emb<<<(50 * 64 + 255) / 256, 256, 0, stream>>>(e0, e1, e2, e3, e4, e5, ebf);
    k_prep_w<12><<<(12 * 16 * 64 + 255) / 256, 256, 0, stream>>>(W1, Wt1);
    k_prep_w<4><<<(4 * 16 * 64 + 255) / 256, 256, 0, stream>>>(W2, Wt2);
    k_hist<<<(ETOT + 255) / 256, 256, 0, stream>>>(ei, deg);
    k_scan1<<<nb, 256, 0, stream>>>(deg, offs, bsum);
    k_scan2<<<1, 64, 0, stream>>>(bsum, nb, offs);
    k_scan3<<<nb, 256, 0, stream>>>(offs, bsum);
    k_scatter<<<(ETOT + 255) / 256, 256, 0, stream>>>(ei, offs, cur, csrc);

    // layer 1
    {
        dim3 grid(4, (NN + 127) / 128);
        k_gemm_mfma<0, 12><<<grid, 256, 0, stream>>>(x, ebf, nullptr, Wt1, xwb, NN);
    }
    k_sd2<2><<<nwb, 256, 0, stream>>>(xwb, as1, ad1, sbuf, dbuf);
    k_agg1<<<nwb, 256, 0, stream>>>(xwb, sbuf, dbuf, offs, csrc, b1, h1b);

    // layer 2
    {
        dim3 grid(4, (NN + 127) / 128);
        k_gemm_mfma<1, 4><<<grid, 256, 0, stream>>>(x, ebf, h1b, Wt2, xwb, NN);
    }
    k_sd2<4><<<nwb, 256, 0, stream>>>(xwb, as2, ad2, sbuf, dbuf);
    k_agg2<<<nwb, 256, 0, stream>>>(xwb, sbuf, dbuf, offs, csrc, b2, bat, gsum);

    // final
    k_final<<<GG, 64, 0, stream>>>(gsum, lw, lb, out);
}